// Round 10
// baseline (807.876 us; speedup 1.0000x reference)
//
#include <hip/hip_runtime.h>
#include <hip/hip_fp16.h>

#define BN_EPS 1e-5f

// ---------- degree count (int) ----------
__global__ void k_zero_i(int* __restrict__ p, int n) {
    int i = blockIdx.x * blockDim.x + threadIdx.x;
    if (i < n) p[i] = 0;
}

__global__ void k_count(const int* __restrict__ dst, int* __restrict__ cnt, int E) {
    int e = blockIdx.x * blockDim.x + threadIdx.x;
    if (e < E) atomicAdd(&cnt[dst[e]], 1);
}

__global__ void k_dinv(const int* __restrict__ cnt, float* __restrict__ dinv, int n) {
    int i = blockIdx.x * blockDim.x + threadIdx.x;
    if (i < n) dinv[i] = rsqrtf((float)(cnt[i] + 1));   // +1 self loop
}

// ---------- exclusive scan (two-level) ----------
__global__ void k_scan1(const int* __restrict__ cnt, int* __restrict__ rs,
                        int* __restrict__ bsum, int n) {
    __shared__ int sh[1024];
    const int t = threadIdx.x;
    const int gid = blockIdx.x * 1024 + t;
    int v = (gid < n) ? cnt[gid] : 0;
    sh[t] = v;
    __syncthreads();
    for (int off = 1; off < 1024; off <<= 1) {
        int u = (t >= off) ? sh[t - off] : 0;
        __syncthreads();
        sh[t] += u;
        __syncthreads();
    }
    if (gid < n) rs[gid] = sh[t] - v;       // exclusive
    if (t == 1023) bsum[blockIdx.x] = sh[1023];
}

__global__ void k_scan2(int* __restrict__ bsum, int nb) {
    __shared__ int sh[1024];
    const int t = threadIdx.x;
    int v = (t < nb) ? bsum[t] : 0;
    sh[t] = v;
    __syncthreads();
    for (int off = 1; off < 1024; off <<= 1) {
        int u = (t >= off) ? sh[t - off] : 0;
        __syncthreads();
        sh[t] += u;
        __syncthreads();
    }
    if (t < nb) bsum[t] = sh[t] - v;        // exclusive
}

__global__ void k_scan3(int* __restrict__ rs, int* __restrict__ cur,
                        const int* __restrict__ bsum, int n) {
    int i = blockIdx.x * blockDim.x + threadIdx.x;
    if (i < n) {
        int v = rs[i] + bsum[i >> 10];
        rs[i] = v;
        cur[i] = v;
    }
}

// ---------- XCD-affine direct CSR fill (R8, works) ----------
__global__ void k_fillx(const int* __restrict__ src, const int* __restrict__ dst,
                        int* __restrict__ cur, int* __restrict__ csrc,
                        int E, int nchunk) {
    const int chunk = blockIdx.x >> 3;
    const int myx = blockIdx.x & 7;
    const int per = (E + nchunk - 1) / nchunk;
    const int lo = chunk * per;
    const int hi = min(lo + per, E);
    for (int e = lo + threadIdx.x; e < hi; e += blockDim.x) {
        int d = dst[e];
        if (((d >> 7) & 7) == myx) {
            int pos = atomicAdd(&cur[d], 1);
            csrc[pos] = src[e];
        }
    }
}

// ---------- degree counting-sort: perm groups nodes of equal indegree ----------
// 64 bins x 64 node-slices; hist layout hist[deg*64 + slice]. LDS cursors in
// fill -> zero global atomic contention (R5 lesson).
__global__ void k_dhist(const int* __restrict__ cnt, int* __restrict__ hist, int n) {
    __shared__ int lh[64];
    const int b = blockIdx.x;
    if (threadIdx.x < 64) lh[threadIdx.x] = 0;
    __syncthreads();
    const int S = (n + 63) >> 6;
    const int lo = b * S, hi = min(lo + S, n);
    for (int i = lo + threadIdx.x; i < hi; i += blockDim.x)
        atomicAdd(&lh[min(cnt[i], 63)], 1);
    __syncthreads();
    if (threadIdx.x < 64) hist[threadIdx.x * 64 + b] = lh[threadIdx.x];
}

__global__ void k_dscan(int* __restrict__ hist) {   // 4096 entries, 1 block
    __shared__ int sh[1024];
    const int t = threadIdx.x;
    int v[4]; int s = 0;
    #pragma unroll
    for (int k = 0; k < 4; ++k) { v[k] = hist[t * 4 + k]; s += v[k]; }
    sh[t] = s;
    __syncthreads();
    for (int off = 1; off < 1024; off <<= 1) {
        int u = (t >= off) ? sh[t - off] : 0;
        __syncthreads();
        sh[t] += u;
        __syncthreads();
    }
    int base = sh[t] - s;   // exclusive
    #pragma unroll
    for (int k = 0; k < 4; ++k) { hist[t * 4 + k] = base; base += v[k]; }
}

__global__ void k_dfill(const int* __restrict__ cnt, const int* __restrict__ hist,
                        int* __restrict__ perm, int n) {
    __shared__ int lcur[64];
    const int b = blockIdx.x;
    if (threadIdx.x < 64) lcur[threadIdx.x] = hist[threadIdx.x * 64 + b];
    __syncthreads();
    const int S = (n + 63) >> 6;
    const int lo = b * S, hi = min(lo + S, n);
    for (int i = lo + threadIdx.x; i < hi; i += blockDim.x) {
        int pos = atomicAdd(&lcur[min(cnt[i], 63)], 1);
        perm[pos] = i;
    }
}

// ---------- x -> fp16 convert ----------
__global__ void k_x2h(const float* __restrict__ x, __half* __restrict__ xh, int total4) {
    int i = blockIdx.x * blockDim.x + threadIdx.x;
    int idx = i * 4;
    if (idx < total4 * 4) {
        float4 v = *(const float4*)&x[idx];
        union { uint2 u; __half2 h[2]; } o;
        o.h[0] = __floats2half2_rn(v.x, v.y);
        o.h[1] = __floats2half2_rn(v.z, v.w);
        *(uint2*)&xh[idx] = o.u;
    }
}

// ---------- layer-1 pre-aggregation on fp16 x (24-wide, degree-ordered) ----------
__global__ void k_agg24h(const __half* __restrict__ xh, const int* __restrict__ rs,
                         const int* __restrict__ rend, const int* __restrict__ csrc,
                         const float* __restrict__ dinv, const int* __restrict__ perm,
                         float* __restrict__ XA, int n) {
    const int g = threadIdx.x >> 3;
    const int j = threadIdx.x & 7;
    const bool act = (j < 6);
    union U { uint2 u; __half2 h[2]; };
    for (int ii = blockIdx.x * 32 + g; ii < n; ii += gridDim.x * 32) {
        const int d = __builtin_nontemporal_load(&perm[ii]);
        const float di = dinv[d];
        const int beg = rs[d], end = rend[d];
        float4 acc = make_float4(0.f, 0.f, 0.f, 0.f);
        if (act) {
            U u; u.u = *(const uint2*)&xh[(size_t)d * 24 + 4 * j];
            float2 f0 = __half22float2(u.h[0]), f1 = __half22float2(u.h[1]);
            acc.x = f0.x * di; acc.y = f0.y * di; acc.z = f1.x * di; acc.w = f1.y * di;
        }
        int e = beg;
        for (; e + 3 < end; e += 4) {
            int s0 = csrc[e], s1 = csrc[e + 1], s2 = csrc[e + 2], s3 = csrc[e + 3];
            float w0 = dinv[s0], w1 = dinv[s1], w2 = dinv[s2], w3 = dinv[s3];
            if (act) {
                U u0, u1, u2, u3;
                u0.u = *(const uint2*)&xh[(size_t)s0 * 24 + 4 * j];
                u1.u = *(const uint2*)&xh[(size_t)s1 * 24 + 4 * j];
                u2.u = *(const uint2*)&xh[(size_t)s2 * 24 + 4 * j];
                u3.u = *(const uint2*)&xh[(size_t)s3 * 24 + 4 * j];
                float2 a0 = __half22float2(u0.h[0]), b0 = __half22float2(u0.h[1]);
                float2 a1 = __half22float2(u1.h[0]), b1 = __half22float2(u1.h[1]);
                float2 a2 = __half22float2(u2.h[0]), b2 = __half22float2(u2.h[1]);
                float2 a3 = __half22float2(u3.h[0]), b3 = __half22float2(u3.h[1]);
                acc.x = fmaf(a0.x, w0, acc.x); acc.y = fmaf(a0.y, w0, acc.y);
                acc.z = fmaf(b0.x, w0, acc.z); acc.w = fmaf(b0.y, w0, acc.w);
                acc.x = fmaf(a1.x, w1, acc.x); acc.y = fmaf(a1.y, w1, acc.y);
                acc.z = fmaf(b1.x, w1, acc.z); acc.w = fmaf(b1.y, w1, acc.w);
                acc.x = fmaf(a2.x, w2, acc.x); acc.y = fmaf(a2.y, w2, acc.y);
                acc.z = fmaf(b2.x, w2, acc.z); acc.w = fmaf(b2.y, w2, acc.w);
                acc.x = fmaf(a3.x, w3, acc.x); acc.y = fmaf(a3.y, w3, acc.y);
                acc.z = fmaf(b3.x, w3, acc.z); acc.w = fmaf(b3.y, w3, acc.w);
            }
        }
        for (; e < end; ++e) {
            int s = csrc[e];
            float w = dinv[s];
            if (act) {
                U u; u.u = *(const uint2*)&xh[(size_t)s * 24 + 4 * j];
                float2 f0 = __half22float2(u.h[0]), f1 = __half22float2(u.h[1]);
                acc.x = fmaf(f0.x, w, acc.x); acc.y = fmaf(f0.y, w, acc.y);
                acc.z = fmaf(f1.x, w, acc.z); acc.w = fmaf(f1.y, w, acc.w);
            }
        }
        if (act) {
            acc.x *= di; acc.y *= di; acc.z *= di; acc.w *= di;
            *(float4*)&XA[(size_t)d * 24 + 4 * j] = acc;
        }
    }
}

// ---------- GEMM: out = (X*aff_a + aff_c) @ W ----------
// CMIN: input X is chunk-major f32 [K/16][n][16]; else row-major [n][K].
// EPI=true : out = relu(acc+b), chunk-major f32 [F/16][n][16] + column stats
// EPI=false: out = acc, chunk-major fp16 [F/16][n][16]
template<int K, int F, int RT, bool AFF, bool EPI, bool CMIN>
__global__ __launch_bounds__(256) void k_gemm2(const float* __restrict__ X,
        const float* __restrict__ W, const float* __restrict__ aff,
        void* __restrict__ Ov, const float* __restrict__ b,
        float* __restrict__ sums, int n) {
    constexpr int COLG = F / 4;
    constexpr int ROWG = 256 / COLG;
    constexpr int TR = ROWG * RT;
    __shared__ float sW[K * F];
    __shared__ float sX[TR * K];
    __shared__ float sRed[2 * F];
    const int tid = threadIdx.x;
    const int tx = tid % COLG;
    const int ty = tid / COLG;

    for (int i = tid * 4; i < K * F; i += 1024)
        *(float4*)&sW[i] = *(const float4*)&W[i];

    float4 bv;
    float ls[4], lq[4];
    if constexpr (EPI) {
        bv = *(const float4*)&b[tx * 4];
        #pragma unroll
        for (int c = 0; c < 4; ++c) { ls[c] = 0.f; lq[c] = 0.f; }
    }

    const int ntiles = (n + TR - 1) / TR;
    for (int tile = blockIdx.x; tile < ntiles; tile += gridDim.x) {
        const int r0 = tile * TR;
        __syncthreads();
        for (int i = tid * 4; i < TR * K; i += 1024) {
            const int row = i / K;
            const int kk = i % K;
            float4 v;
            if (r0 + row < n) {
                if constexpr (CMIN)
                    v = *(const float4*)&X[((size_t)(kk >> 4) * n + (r0 + row)) * 16 + (kk & 15)];
                else
                    v = *(const float4*)&X[(size_t)(r0 + row) * K + kk];
                if constexpr (AFF) {
                    v.x = fmaf(v.x, aff[kk],     aff[K + kk]);
                    v.y = fmaf(v.y, aff[kk + 1], aff[K + kk + 1]);
                    v.z = fmaf(v.z, aff[kk + 2], aff[K + kk + 2]);
                    v.w = fmaf(v.w, aff[kk + 3], aff[K + kk + 3]);
                }
            } else {
                v = make_float4(0.f, 0.f, 0.f, 0.f);
            }
            *(float4*)&sX[i] = v;
        }
        __syncthreads();

        float acc[RT][4];
        #pragma unroll
        for (int r = 0; r < RT; ++r)
            #pragma unroll
            for (int c = 0; c < 4; ++c) acc[r][c] = 0.0f;

        for (int k4 = 0; k4 < K; k4 += 4) {
            float xk[RT][4];
            #pragma unroll
            for (int r = 0; r < RT; ++r) {
                float4 t = *(const float4*)&sX[(ty * RT + r) * K + k4];
                xk[r][0] = t.x; xk[r][1] = t.y; xk[r][2] = t.z; xk[r][3] = t.w;
            }
            float4 wv[4];
            #pragma unroll
            for (int kk = 0; kk < 4; ++kk)
                wv[kk] = *(const float4*)&sW[(k4 + kk) * F + tx * 4];
            #pragma unroll
            for (int kk = 0; kk < 4; ++kk)
                #pragma unroll
                for (int r = 0; r < RT; ++r) {
                    const float xr = xk[r][kk];
                    acc[r][0] = fmaf(xr, wv[kk].x, acc[r][0]);
                    acc[r][1] = fmaf(xr, wv[kk].y, acc[r][1]);
                    acc[r][2] = fmaf(xr, wv[kk].z, acc[r][2]);
                    acc[r][3] = fmaf(xr, wv[kk].w, acc[r][3]);
                }
        }

        #pragma unroll
        for (int r = 0; r < RT; ++r) {
            const int row = r0 + ty * RT + r;
            if (row < n) {
                const int col = tx * 4;
                const size_t oidx = ((size_t)(col >> 4) * n + row) * 16 + (col & 15);
                if constexpr (EPI) {
                    float4 o;
                    o.x = fmaxf(acc[r][0] + bv.x, 0.f);
                    o.y = fmaxf(acc[r][1] + bv.y, 0.f);
                    o.z = fmaxf(acc[r][2] + bv.z, 0.f);
                    o.w = fmaxf(acc[r][3] + bv.w, 0.f);
                    ls[0] += o.x; lq[0] += o.x * o.x;
                    ls[1] += o.y; lq[1] += o.y * o.y;
                    ls[2] += o.z; lq[2] += o.z * o.z;
                    ls[3] += o.w; lq[3] += o.w * o.w;
                    *(float4*)&((float*)Ov)[oidx] = o;
                } else {
                    union { float2 f2; __half2 h2[2]; } u;
                    u.h2[0] = __floats2half2_rn(acc[r][0], acc[r][1]);
                    u.h2[1] = __floats2half2_rn(acc[r][2], acc[r][3]);
                    *(float2*)&((__half*)Ov)[oidx] = u.f2;
                }
            }
        }
    }

    if constexpr (EPI) {
        __syncthreads();
        if (tid < 2 * F) sRed[tid] = 0.f;
        __syncthreads();
        #pragma unroll
        for (int c = 0; c < 4; ++c) {
            atomicAdd(&sRed[tx * 4 + c], ls[c]);
            atomicAdd(&sRed[F + tx * 4 + c], lq[c]);
        }
        __syncthreads();
        if (tid < F) {
            atomicAdd(&sums[tid], sRed[tid]);
            atomicAdd(&sums[F + tid], sRed[F + tid]);
        }
    }
}

// ---------- chunked XCD-affine fp16 gather agg, degree-ordered + nt streams ----------
// H chunk-major fp16 [NC][n][16]; A out chunk-major f32 [NC][n][16].
// chunk = blockIdx&7 (~XCD) -> each XCD's L2 caches ONE 3.2MB plane.
// perm orders nodes by indegree -> the 32 nodes of a block iter (8 per wave)
// have ~equal degree -> no exec-mask waste. csrc/perm/rs/A use non-temporal
// ops so streamed-once data doesn't evict the plane.
template<int NC>
__global__ __launch_bounds__(256) void k_aggc(const __half2* __restrict__ Hc,
        const int* __restrict__ rs, const int* __restrict__ rend,
        const int* __restrict__ csrc, const float* __restrict__ dinv,
        const int* __restrict__ perm, const float* __restrict__ b,
        float* __restrict__ A, float* __restrict__ sums, int n) {
    constexpr int F = NC * 16;
    const int xcd = blockIdx.x & 7;
    const int seq = blockIdx.x >> 3;
    const int bpx = gridDim.x >> 3;
    int chunk, bindex, nper;
    if constexpr (NC == 8) { chunk = xcd; bindex = seq; nper = bpx; }
    else { chunk = xcd >> 1; bindex = seq * 2 + (xcd & 1); nper = bpx * 2; }
    const __half2* __restrict__ Hp = Hc + (size_t)chunk * n * 8;
    const int g = threadIdx.x >> 3;
    const int fl = threadIdx.x & 7;
    const int col = chunk * 16 + 2 * fl;
    const float2 bv = make_float2(b[col], b[col + 1]);
    float ls0 = 0.f, lq0 = 0.f, ls1 = 0.f, lq1 = 0.f;

    for (int ii = bindex * 32 + g; ii < n; ii += nper * 32) {
        const int d = __builtin_nontemporal_load(&perm[ii]);
        const int beg = __builtin_nontemporal_load(&rs[d]);
        const int end = __builtin_nontemporal_load(&rend[d]);
        const float di = dinv[d];
        float2 h = __half22float2(Hp[(size_t)d * 8 + fl]);
        float ax = h.x * di, ay = h.y * di;     // self loop (x di again below)
        int j = beg;
        for (; j + 7 < end; j += 8) {
            int s[8];
            #pragma unroll
            for (int k = 0; k < 8; ++k) s[k] = __builtin_nontemporal_load(&csrc[j + k]);
            float w[8]; __half2 hv[8];
            #pragma unroll
            for (int k = 0; k < 8; ++k) {
                w[k] = dinv[s[k]];
                hv[k] = Hp[(size_t)s[k] * 8 + fl];
            }
            #pragma unroll
            for (int k = 0; k < 8; ++k) {
                float2 f = __half22float2(hv[k]);
                ax = fmaf(f.x, w[k], ax);
                ay = fmaf(f.y, w[k], ay);
            }
        }
        for (; j + 3 < end; j += 4) {
            int s[4];
            #pragma unroll
            for (int k = 0; k < 4; ++k) s[k] = __builtin_nontemporal_load(&csrc[j + k]);
            float w[4]; __half2 hv[4];
            #pragma unroll
            for (int k = 0; k < 4; ++k) {
                w[k] = dinv[s[k]];
                hv[k] = Hp[(size_t)s[k] * 8 + fl];
            }
            #pragma unroll
            for (int k = 0; k < 4; ++k) {
                float2 f = __half22float2(hv[k]);
                ax = fmaf(f.x, w[k], ax);
                ay = fmaf(f.y, w[k], ay);
            }
        }
        for (; j < end; ++j) {
            int s = __builtin_nontemporal_load(&csrc[j]);
            float w = dinv[s];
            float2 f = __half22float2(Hp[(size_t)s * 8 + fl]);
            ax = fmaf(f.x, w, ax);
            ay = fmaf(f.y, w, ay);
        }
        float vx = fmaxf(fmaf(ax, di, bv.x), 0.f);
        float vy = fmaxf(fmaf(ay, di, bv.y), 0.f);
        union { float2 f; double dd; } uo;
        uo.f = make_float2(vx, vy);
        __builtin_nontemporal_store(uo.dd,
            (double*)&A[((size_t)chunk * n + d) * 16 + 2 * fl]);
        ls0 += vx; lq0 += vx * vx;
        ls1 += vy; lq1 += vy * vy;
    }

    __shared__ float sR[32];
    if (threadIdx.x < 32) sR[threadIdx.x] = 0.f;
    __syncthreads();
    atomicAdd(&sR[2 * fl], ls0);
    atomicAdd(&sR[2 * fl + 1], ls1);
    atomicAdd(&sR[16 + 2 * fl], lq0);
    atomicAdd(&sR[16 + 2 * fl + 1], lq1);
    __syncthreads();
    if (threadIdx.x < 16) {
        atomicAdd(&sums[chunk * 16 + threadIdx.x], sR[threadIdx.x]);
        atomicAdd(&sums[F + chunk * 16 + threadIdx.x], sR[16 + threadIdx.x]);
    }
}

// ---------- BN fold ----------
__global__ void k_bnprep(const float* __restrict__ sums, const float* __restrict__ g,
                         const float* __restrict__ be, float* __restrict__ aff,
                         int F, float invn) {
    int f = threadIdx.x;
    if (f < F) {
        float mean = sums[f] * invn;
        float var = sums[F + f] * invn - mean * mean;
        float a = rsqrtf(var + BN_EPS) * g[f];
        aff[f] = a;
        aff[F + f] = be[f] - mean * a;
    }
}

// ---------- final 64->2 GEMM, chunk-major input [4][n][16] ----------
__global__ void k_gemm4(const float* __restrict__ X, const float* __restrict__ W,
                        const float* __restrict__ aff, float* __restrict__ H, int n) {
    int i = blockIdx.x * blockDim.x + threadIdx.x;
    if (i >= n) return;
    float a0 = 0.0f, a1 = 0.0f;
    #pragma unroll 8
    for (int k = 0; k < 64; ++k) {
        float v = X[((size_t)(k >> 4) * n + i) * 16 + (k & 15)] * aff[k] + aff[64 + k];
        a0 = fmaf(v, W[2 * k], a0);
        a1 = fmaf(v, W[2 * k + 1], a1);
    }
    H[2 * i] = a0;
    H[2 * i + 1] = a1;
}

// ---------- final aggregation (F=2) + bias + log_softmax, degree-ordered ----------
__global__ void k_last(const float* __restrict__ H, const int* __restrict__ rs,
                       const int* __restrict__ rend, const int* __restrict__ csrc,
                       const float* __restrict__ dinv, const int* __restrict__ perm,
                       const float* __restrict__ b, float* __restrict__ out, int n) {
    int i = blockIdx.x * blockDim.x + threadIdx.x;
    if (i >= n) return;
    const int d = perm[i];
    const float di = dinv[d];
    float a0 = H[2 * d] * di, a1 = H[2 * d + 1] * di;
    const int beg = rs[d], end = rend[d];
    for (int j = beg; j < end; ++j) {
        int s = csrc[j];
        float w = dinv[s];
        a0 = fmaf(H[2 * s], w, a0);
        a1 = fmaf(H[2 * s + 1], w, a1);
    }
    float v0 = fmaf(a0, di, b[0]);
    float v1 = fmaf(a1, di, b[1]);
    float m = fmaxf(v0, v1);
    float l = logf(expf(v0 - m) + expf(v1 - m)) + m;
    out[2 * d] = v0 - l;
    out[2 * d + 1] = v1 - l;
}

extern "C" void kernel_launch(void* const* d_in, const int* in_sizes, int n_in,
                              void* d_out, int out_size, void* d_ws, size_t ws_size,
                              hipStream_t stream) {
    const float* x   = (const float*)d_in[0];
    const int*   ei  = (const int*)d_in[1];
    const float* W1  = (const float*)d_in[2];
    const float* b1  = (const float*)d_in[3];
    const float* g1  = (const float*)d_in[4];
    const float* be1 = (const float*)d_in[5];
    const float* W2  = (const float*)d_in[6];
    const float* b2  = (const float*)d_in[7];
    const float* g2  = (const float*)d_in[8];
    const float* be2 = (const float*)d_in[9];
    const float* W3  = (const float*)d_in[10];
    const float* b3  = (const float*)d_in[11];
    const float* g3  = (const float*)d_in[12];
    const float* be3 = (const float*)d_in[13];
    const float* W4  = (const float*)d_in[14];
    const float* b4  = (const float*)d_in[15];
    float* out = (float*)d_out;

    const int N = in_sizes[0] / 24;
    const int E = in_sizes[1] / 2;
    const int* srcI = ei;
    const int* dstI = ei + E;

    // ---- workspace carve ----
    int* cnt   = (int*)d_ws;                 // N
    int* rs    = cnt + N;                    // N
    int* cur   = rs + N;                     // N
    int* csrc  = cur + N;                    // E
    int* bsum  = csrc + E;                   // 1024
    int* perm  = bsum + 1024;                // N
    int* hist  = perm + N;                   // 4096
    float* dinv = (float*)(hist + 4096);     // N
    float* Hbase = dinv + N;                 // N*128 f32 region (multi-use)
    float* A    = Hbase + (size_t)N * 128;   // N*128 f32 (chunk-major planes)
    float* S    = A + (size_t)N * 128;       // 1280 stats
    float* sums1 = S,        *aff1 = S + 256;
    float* sums2 = S + 512,  *aff2 = S + 768;
    float* sums3 = S + 1024, *aff3 = S + 1152;
    // aliases of Hbase (disjoint lifetimes, stream-ordered):
    float*  XA    = Hbase;                   // N*24 f32 (layer-1 pre-agg out, row-major)
    __half* Hh    = (__half*)Hbase;          // N*128 fp16 chunk-major (layers 2/3)
    float*  LG    = Hbase;                   // N*2 logits (layer 4)
    // alias of A (dead until gemm1 writes it):
    __half* xh    = (__half*)A;              // N*24 fp16 copy of x

    hipMemsetAsync(S, 0, 1280 * sizeof(float), stream);

    const int TB = 256;
    const int nb1024 = (N + 1023) / 1024;

    // ---- CSR build + dinv + degree sort ----
    k_zero_i<<<(N + TB - 1) / TB, TB, 0, stream>>>(cnt, N);
    k_count<<<(E + TB - 1) / TB, TB, 0, stream>>>(dstI, cnt, E);
    k_dinv<<<(N + TB - 1) / TB, TB, 0, stream>>>(cnt, dinv, N);
    k_scan1<<<nb1024, 1024, 0, stream>>>(cnt, rs, bsum, N);
    k_scan2<<<1, 1024, 0, stream>>>(bsum, nb1024);
    k_scan3<<<(N + TB - 1) / TB, TB, 0, stream>>>(rs, cur, bsum, N);
    k_fillx<<<256 * 8, TB, 0, stream>>>(srcI, dstI, cur, csrc, E, 256);
    k_dhist<<<64, TB, 0, stream>>>(cnt, hist, N);
    k_dscan<<<1, 1024, 0, stream>>>(hist);
    k_dfill<<<64, TB, 0, stream>>>(cnt, hist, perm, N);
    // after k_fillx, cur[d] == row end

    // ----- layer 1: fp16 x, pre-aggregate (24-wide), GEMM 24->128 + epilogue -----
    k_x2h<<<(N * 24 / 4 + TB - 1) / TB, TB, 0, stream>>>(x, xh, N * 24 / 4);
    k_agg24h<<<2048, 256, 0, stream>>>(xh, rs, cur, csrc, dinv, perm, XA, N);
    k_gemm2<24, 128, 4, false, true, false><<<1024, 256, 0, stream>>>(XA, W1, nullptr, A, b1, sums1, N);
    k_bnprep<<<1, 128, 0, stream>>>(sums1, g1, be1, aff1, 128, 1.0f / (float)N);

    // ----- layer 2: GEMM 128->128 (fp16 chunk-major), chunked agg -----
    k_gemm2<128, 128, 4, true, false, true><<<1024, 256, 0, stream>>>(A, W2, aff1, Hh, nullptr, nullptr, N);
    k_aggc<8><<<2048, 256, 0, stream>>>((const __half2*)Hh, rs, cur, csrc, dinv, perm, b2, A, sums2, N);
    k_bnprep<<<1, 128, 0, stream>>>(sums2, g2, be2, aff2, 128, 1.0f / (float)N);

    // ----- layer 3: GEMM 128->64 (fp16 chunk-major), chunked agg -----
    k_gemm2<128, 64, 2, true, false, true><<<1024, 256, 0, stream>>>(A, W3, aff2, Hh, nullptr, nullptr, N);
    k_aggc<4><<<2048, 256, 0, stream>>>((const __half2*)Hh, rs, cur, csrc, dinv, perm, b3, A, sums3, N);
    k_bnprep<<<1, 64, 0, stream>>>(sums3, g3, be3, aff3, 64, 1.0f / (float)N);

    // ----- layer 4: 64 -> 2 (chunk-major in), log_softmax -----
    k_gemm4<<<(N + TB - 1) / TB, TB, 0, stream>>>(A, W4, aff3, LG, N);
    k_last<<<(N + TB - 1) / TB, TB, 0, stream>>>(LG, rs, cur, csrc, dinv, perm, b4, out, N);
}

// Round 11
// 542.845 us; speedup vs baseline: 1.4882x; 1.4882x over previous
//
#include <hip/hip_runtime.h>
#include <hip/hip_fp16.h>

#define BN_EPS 1e-5f

// ---------- degree count (int) ----------
__global__ void k_zero_i(int* __restrict__ p, int n) {
    int i = blockIdx.x * blockDim.x + threadIdx.x;
    if (i < n) p[i] = 0;
}

__global__ void k_count(const int* __restrict__ dst, int* __restrict__ cnt, int E) {
    int e = blockIdx.x * blockDim.x + threadIdx.x;
    if (e < E) atomicAdd(&cnt[dst[e]], 1);
}

__global__ void k_dinv(const int* __restrict__ cnt, float* __restrict__ dinv, int n) {
    int i = blockIdx.x * blockDim.x + threadIdx.x;
    if (i < n) dinv[i] = rsqrtf((float)(cnt[i] + 1));   // +1 self loop
}

// ---------- exclusive scan (two-level) ----------
__global__ void k_scan1(const int* __restrict__ cnt, int* __restrict__ rs,
                        int* __restrict__ bsum, int n) {
    __shared__ int sh[1024];
    const int t = threadIdx.x;
    const int gid = blockIdx.x * 1024 + t;
    int v = (gid < n) ? cnt[gid] : 0;
    sh[t] = v;
    __syncthreads();
    for (int off = 1; off < 1024; off <<= 1) {
        int u = (t >= off) ? sh[t - off] : 0;
        __syncthreads();
        sh[t] += u;
        __syncthreads();
    }
    if (gid < n) rs[gid] = sh[t] - v;       // exclusive
    if (t == 1023) bsum[blockIdx.x] = sh[1023];
}

__global__ void k_scan2(int* __restrict__ bsum, int nb) {
    __shared__ int sh[1024];
    const int t = threadIdx.x;
    int v = (t < nb) ? bsum[t] : 0;
    sh[t] = v;
    __syncthreads();
    for (int off = 1; off < 1024; off <<= 1) {
        int u = (t >= off) ? sh[t - off] : 0;
        __syncthreads();
        sh[t] += u;
        __syncthreads();
    }
    if (t < nb) bsum[t] = sh[t] - v;        // exclusive
}

__global__ void k_scan3(int* __restrict__ rs, int* __restrict__ cur,
                        const int* __restrict__ bsum, int n) {
    int i = blockIdx.x * blockDim.x + threadIdx.x;
    if (i < n) {
        int v = rs[i] + bsum[i >> 10];
        rs[i] = v;
        cur[i] = v;
    }
}

// ---------- XCD-affine direct CSR fill (R8, works) ----------
__global__ void k_fillx(const int* __restrict__ src, const int* __restrict__ dst,
                        int* __restrict__ cur, int* __restrict__ csrc,
                        int E, int nchunk) {
    const int chunk = blockIdx.x >> 3;
    const int myx = blockIdx.x & 7;
    const int per = (E + nchunk - 1) / nchunk;
    const int lo = chunk * per;
    const int hi = min(lo + per, E);
    for (int e = lo + threadIdx.x; e < hi; e += blockDim.x) {
        int d = dst[e];
        if (((d >> 7) & 7) == myx) {
            int pos = atomicAdd(&cur[d], 1);
            csrc[pos] = src[e];
        }
    }
}

// ---------- x -> fp16 convert, pre-scaled by dinv: x̂[i] = x[i]*dinv[i] ----------
__global__ void k_x2h(const float* __restrict__ x, const float* __restrict__ dinv,
                      __half* __restrict__ xh, int n) {
    int i = blockIdx.x * blockDim.x + threadIdx.x;   // over n*6 float4 groups
    if (i < n * 6) {
        int node = i / 6;
        int j = i - node * 6;
        float dv = dinv[node];
        float4 v = *(const float4*)&x[(size_t)node * 24 + j * 4];
        union { uint2 u; __half2 h[2]; } o;
        o.h[0] = __floats2half2_rn(v.x * dv, v.y * dv);
        o.h[1] = __floats2half2_rn(v.z * dv, v.w * dv);
        *(uint2*)&xh[(size_t)node * 24 + j * 4] = o.u;
    }
}

// ---------- layer-1 pre-aggregation on pre-scaled fp16 x̂ (24-wide) ----------
// XA[d] = dinv[d] * (x̂[d] + Σ x̂[s])   (x̂ already carries dinv[src])
__global__ void k_agg24h(const __half* __restrict__ xh, const int* __restrict__ rs,
                         const int* __restrict__ rend, const int* __restrict__ csrc,
                         const float* __restrict__ dinv, float* __restrict__ XA, int n) {
    const int g = threadIdx.x >> 3;
    const int j = threadIdx.x & 7;
    const bool act = (j < 6);
    union U { uint2 u; __half2 h[2]; };
    for (int d = blockIdx.x * 32 + g; d < n; d += gridDim.x * 32) {
        const float di = dinv[d];
        const int beg = rs[d], end = rend[d];
        float4 acc = make_float4(0.f, 0.f, 0.f, 0.f);
        if (act) {
            U u; u.u = *(const uint2*)&xh[(size_t)d * 24 + 4 * j];
            float2 f0 = __half22float2(u.h[0]), f1 = __half22float2(u.h[1]);
            acc.x = f0.x; acc.y = f0.y; acc.z = f1.x; acc.w = f1.y;
        }
        int e = beg;
        for (; e + 3 < end; e += 4) {
            int s0 = csrc[e], s1 = csrc[e + 1], s2 = csrc[e + 2], s3 = csrc[e + 3];
            if (act) {
                U u0, u1, u2, u3;
                u0.u = *(const uint2*)&xh[(size_t)s0 * 24 + 4 * j];
                u1.u = *(const uint2*)&xh[(size_t)s1 * 24 + 4 * j];
                u2.u = *(const uint2*)&xh[(size_t)s2 * 24 + 4 * j];
                u3.u = *(const uint2*)&xh[(size_t)s3 * 24 + 4 * j];
                float2 a0 = __half22float2(u0.h[0]), b0 = __half22float2(u0.h[1]);
                float2 a1 = __half22float2(u1.h[0]), b1 = __half22float2(u1.h[1]);
                float2 a2 = __half22float2(u2.h[0]), b2 = __half22float2(u2.h[1]);
                float2 a3 = __half22float2(u3.h[0]), b3 = __half22float2(u3.h[1]);
                acc.x += a0.x + a1.x; acc.y += a0.y + a1.y;
                acc.z += b0.x + b1.x; acc.w += b0.y + b1.y;
                acc.x += a2.x + a3.x; acc.y += a2.y + a3.y;
                acc.z += b2.x + b3.x; acc.w += b2.y + b3.y;
            }
        }
        for (; e < end; ++e) {
            int s = csrc[e];
            if (act) {
                U u; u.u = *(const uint2*)&xh[(size_t)s * 24 + 4 * j];
                float2 f0 = __half22float2(u.h[0]), f1 = __half22float2(u.h[1]);
                acc.x += f0.x; acc.y += f0.y; acc.z += f1.x; acc.w += f1.y;
            }
        }
        if (act) {
            acc.x *= di; acc.y *= di; acc.z *= di; acc.w *= di;
            *(float4*)&XA[(size_t)d * 24 + 4 * j] = acc;
        }
    }
}

// ---------- GEMM: out = (X*aff_a + aff_c) @ W, row-major in/out ----------
// EPI=true : O=float*, out = relu(acc + b) + column stats (layer 1)
// EPI=false: O=__half*, out = acc * dinv[row]  (pre-scaled Ĥ for gather agg)
template<int K, int F, int RT, bool AFF, bool EPI>
__global__ __launch_bounds__(256) void k_gemm2(const float* __restrict__ X,
        const float* __restrict__ W, const float* __restrict__ aff,
        void* __restrict__ Ov, const float* __restrict__ b,
        float* __restrict__ sums, const float* __restrict__ dinv, int n) {
    constexpr int COLG = F / 4;
    constexpr int ROWG = 256 / COLG;
    constexpr int TR = ROWG * RT;
    __shared__ float sW[K * F];
    __shared__ float sX[TR * K];
    __shared__ float sRed[2 * F];
    const int tid = threadIdx.x;
    const int tx = tid % COLG;
    const int ty = tid / COLG;

    for (int i = tid * 4; i < K * F; i += 1024)
        *(float4*)&sW[i] = *(const float4*)&W[i];

    float4 bv;
    float ls[4], lq[4];
    if constexpr (EPI) {
        bv = *(const float4*)&b[tx * 4];
        #pragma unroll
        for (int c = 0; c < 4; ++c) { ls[c] = 0.f; lq[c] = 0.f; }
    }

    const int ntiles = (n + TR - 1) / TR;
    for (int tile = blockIdx.x; tile < ntiles; tile += gridDim.x) {
        const int r0 = tile * TR;
        __syncthreads();
        for (int i = tid * 4; i < TR * K; i += 1024) {
            const int row = i / K;
            const int kk = i % K;
            float4 v;
            if (r0 + row < n) {
                v = *(const float4*)&X[(size_t)(r0 + row) * K + kk];
                if constexpr (AFF) {
                    v.x = fmaf(v.x, aff[kk],     aff[K + kk]);
                    v.y = fmaf(v.y, aff[kk + 1], aff[K + kk + 1]);
                    v.z = fmaf(v.z, aff[kk + 2], aff[K + kk + 2]);
                    v.w = fmaf(v.w, aff[kk + 3], aff[K + kk + 3]);
                }
            } else {
                v = make_float4(0.f, 0.f, 0.f, 0.f);
            }
            *(float4*)&sX[i] = v;
        }
        __syncthreads();

        float acc[RT][4];
        #pragma unroll
        for (int r = 0; r < RT; ++r)
            #pragma unroll
            for (int c = 0; c < 4; ++c) acc[r][c] = 0.0f;

        for (int k4 = 0; k4 < K; k4 += 4) {
            float xk[RT][4];
            #pragma unroll
            for (int r = 0; r < RT; ++r) {
                float4 t = *(const float4*)&sX[(ty * RT + r) * K + k4];
                xk[r][0] = t.x; xk[r][1] = t.y; xk[r][2] = t.z; xk[r][3] = t.w;
            }
            float4 wv[4];
            #pragma unroll
            for (int kk = 0; kk < 4; ++kk)
                wv[kk] = *(const float4*)&sW[(k4 + kk) * F + tx * 4];
            #pragma unroll
            for (int kk = 0; kk < 4; ++kk)
                #pragma unroll
                for (int r = 0; r < RT; ++r) {
                    const float xr = xk[r][kk];
                    acc[r][0] = fmaf(xr, wv[kk].x, acc[r][0]);
                    acc[r][1] = fmaf(xr, wv[kk].y, acc[r][1]);
                    acc[r][2] = fmaf(xr, wv[kk].z, acc[r][2]);
                    acc[r][3] = fmaf(xr, wv[kk].w, acc[r][3]);
                }
        }

        #pragma unroll
        for (int r = 0; r < RT; ++r) {
            const int row = r0 + ty * RT + r;
            if (row < n) {
                if constexpr (EPI) {
                    float4 o;
                    o.x = fmaxf(acc[r][0] + bv.x, 0.f);
                    o.y = fmaxf(acc[r][1] + bv.y, 0.f);
                    o.z = fmaxf(acc[r][2] + bv.z, 0.f);
                    o.w = fmaxf(acc[r][3] + bv.w, 0.f);
                    ls[0] += o.x; lq[0] += o.x * o.x;
                    ls[1] += o.y; lq[1] += o.y * o.y;
                    ls[2] += o.z; lq[2] += o.z * o.z;
                    ls[3] += o.w; lq[3] += o.w * o.w;
                    *(float4*)&((float*)Ov)[(size_t)row * F + tx * 4] = o;
                } else {
                    const float dv = dinv[row];
                    union { float2 f2; __half2 h2[2]; } u;
                    u.h2[0] = __floats2half2_rn(acc[r][0] * dv, acc[r][1] * dv);
                    u.h2[1] = __floats2half2_rn(acc[r][2] * dv, acc[r][3] * dv);
                    *(float2*)&((__half*)Ov)[(size_t)row * F + tx * 4] = u.f2;
                }
            }
        }
    }

    if constexpr (EPI) {
        __syncthreads();
        if (tid < 2 * F) sRed[tid] = 0.f;
        __syncthreads();
        #pragma unroll
        for (int c = 0; c < 4; ++c) {
            atomicAdd(&sRed[tx * 4 + c], ls[c]);
            atomicAdd(&sRed[F + tx * 4 + c], lq[c]);
        }
        __syncthreads();
        if (tid < F) {
            atomicAdd(&sums[tid], sRed[tid]);
            atomicAdd(&sums[F + tid], sRed[F + tid]);
        }
    }
}

// ---------- half2 CSR gather aggregation on pre-scaled Ĥ ----------
// A[d,:] = relu(dinv[d]*(Ĥ[d] + Σ Ĥ[s]) + b) ; Ĥ carries dinv[src] already.
// F=128: 64 lanes = full row, 1 node/wave (zero divergence). F=64: 2 nodes/wave.
template<int F>
__global__ __launch_bounds__(256) void k_aggh(const __half2* __restrict__ H2,
        const int* __restrict__ rs, const int* __restrict__ rend,
        const int* __restrict__ csrc, const float* __restrict__ dinv,
        const float* __restrict__ b, float* __restrict__ A,
        float* __restrict__ sums, int n) {
    constexpr int LPN = F / 2;           // lanes per node
    constexpr int NPW = 64 / LPN;        // nodes per wave
    __shared__ float sR[2 * F];
    const int tid = threadIdx.x;
    const int lane = tid & 63;
    const int wid = tid >> 6;
    const int sub = lane / LPN;
    const int fl = lane % LPN;
    const float2 bv = make_float2(b[2 * fl], b[2 * fl + 1]);
    const int gw = blockIdx.x * 4 + wid;
    const int nw = gridDim.x * 4;
    float ls0 = 0.f, lq0 = 0.f, ls1 = 0.f, lq1 = 0.f;

    for (int d = gw * NPW + sub; d < n; d += nw * NPW) {
        const int beg = rs[d], end = rend[d];
        const float di = dinv[d];
        float2 h = __half22float2(H2[(size_t)d * LPN + fl]);
        float ax = h.x, ay = h.y;               // Ĥ[d] = H[d]*dinv[d]
        int j = beg;
        for (; j + 7 < end; j += 8) {
            int s[8];
            #pragma unroll
            for (int k = 0; k < 8; ++k) s[k] = csrc[j + k];
            __half2 hv[8];
            #pragma unroll
            for (int k = 0; k < 8; ++k) hv[k] = H2[(size_t)s[k] * LPN + fl];
            #pragma unroll
            for (int k = 0; k < 8; ++k) {
                float2 f = __half22float2(hv[k]);
                ax += f.x;
                ay += f.y;
            }
        }
        for (; j + 3 < end; j += 4) {
            int s[4];
            #pragma unroll
            for (int k = 0; k < 4; ++k) s[k] = csrc[j + k];
            __half2 hv[4];
            #pragma unroll
            for (int k = 0; k < 4; ++k) hv[k] = H2[(size_t)s[k] * LPN + fl];
            #pragma unroll
            for (int k = 0; k < 4; ++k) {
                float2 f = __half22float2(hv[k]);
                ax += f.x;
                ay += f.y;
            }
        }
        for (; j < end; ++j) {
            int s = csrc[j];
            float2 f = __half22float2(H2[(size_t)s * LPN + fl]);
            ax += f.x;
            ay += f.y;
        }
        float vx = fmaxf(fmaf(ax, di, bv.x), 0.f);
        float vy = fmaxf(fmaf(ay, di, bv.y), 0.f);
        *(float2*)&A[(size_t)d * F + 2 * fl] = make_float2(vx, vy);
        ls0 += vx; lq0 += vx * vx;
        ls1 += vy; lq1 += vy * vy;
    }

    if (tid < 2 * F) sR[tid] = 0.f;
    __syncthreads();
    atomicAdd(&sR[2 * fl], ls0);
    atomicAdd(&sR[2 * fl + 1], ls1);
    atomicAdd(&sR[F + 2 * fl], lq0);
    atomicAdd(&sR[F + 2 * fl + 1], lq1);
    __syncthreads();
    if (tid < 2 * F) atomicAdd(&sums[tid], sR[tid]);
}

// ---------- BN fold ----------
__global__ void k_bnprep(const float* __restrict__ sums, const float* __restrict__ g,
                         const float* __restrict__ be, float* __restrict__ aff,
                         int F, float invn) {
    int f = threadIdx.x;
    if (f < F) {
        float mean = sums[f] * invn;
        float var = sums[F + f] * invn - mean * mean;
        float a = rsqrtf(var + BN_EPS) * g[f];
        aff[f] = a;
        aff[F + f] = be[f] - mean * a;
    }
}

// ---------- final 64->2 GEMM with input affine; output pre-scaled by dinv ----------
__global__ void k_gemm4(const float* __restrict__ X, const float* __restrict__ W,
                        const float* __restrict__ aff, const float* __restrict__ dinv,
                        float* __restrict__ H, int n) {
    int i = blockIdx.x * blockDim.x + threadIdx.x;
    if (i >= n) return;
    float a0 = 0.0f, a1 = 0.0f;
    #pragma unroll 8
    for (int k = 0; k < 64; ++k) {
        float v = X[i * 64 + k] * aff[k] + aff[64 + k];
        a0 = fmaf(v, W[2 * k], a0);
        a1 = fmaf(v, W[2 * k + 1], a1);
    }
    const float dv = dinv[i];
    H[2 * i] = a0 * dv;
    H[2 * i + 1] = a1 * dv;
}

// ---------- final aggregation (F=2, pre-scaled) + bias + log_softmax ----------
__global__ void k_last(const float* __restrict__ H, const int* __restrict__ rs,
                       const int* __restrict__ rend, const int* __restrict__ csrc,
                       const float* __restrict__ dinv, const float* __restrict__ b,
                       float* __restrict__ out, int n) {
    int d = blockIdx.x * blockDim.x + threadIdx.x;
    if (d >= n) return;
    const float di = dinv[d];
    float a0 = H[2 * d], a1 = H[2 * d + 1];
    const int beg = rs[d], end = rend[d];
    for (int j = beg; j < end; ++j) {
        int s = csrc[j];
        a0 += H[2 * s];
        a1 += H[2 * s + 1];
    }
    float v0 = fmaf(a0, di, b[0]);
    float v1 = fmaf(a1, di, b[1]);
    float m = fmaxf(v0, v1);
    float l = logf(expf(v0 - m) + expf(v1 - m)) + m;
    out[2 * d] = v0 - l;
    out[2 * d + 1] = v1 - l;
}

extern "C" void kernel_launch(void* const* d_in, const int* in_sizes, int n_in,
                              void* d_out, int out_size, void* d_ws, size_t ws_size,
                              hipStream_t stream) {
    const float* x   = (const float*)d_in[0];
    const int*   ei  = (const int*)d_in[1];
    const float* W1  = (const float*)d_in[2];
    const float* b1  = (const float*)d_in[3];
    const float* g1  = (const float*)d_in[4];
    const float* be1 = (const float*)d_in[5];
    const float* W2  = (const float*)d_in[6];
    const float* b2  = (const float*)d_in[7];
    const float* g2  = (const float*)d_in[8];
    const float* be2 = (const float*)d_in[9];
    const float* W3  = (const float*)d_in[10];
    const float* b3  = (const float*)d_in[11];
    const float* g3  = (const float*)d_in[12];
    const float* be3 = (const float*)d_in[13];
    const float* W4  = (const float*)d_in[14];
    const float* b4  = (const float*)d_in[15];
    float* out = (float*)d_out;

    const int N = in_sizes[0] / 24;
    const int E = in_sizes[1] / 2;
    const int* srcI = ei;
    const int* dstI = ei + E;

    // ---- workspace carve ----
    int* cnt   = (int*)d_ws;                 // N
    int* rs    = cnt + N;                    // N
    int* cur   = rs + N;                     // N
    int* csrc  = cur + N;                    // E
    int* bsum  = csrc + E;                   // 1024
    float* dinv = (float*)(bsum + 1024);     // N
    float* Hbase = dinv + N;                 // N*128 f32 region (multi-use)
    float* A    = Hbase + (size_t)N * 128;   // N*128 f32
    float* S    = A + (size_t)N * 128;       // 1280 stats
    float* sums1 = S,        *aff1 = S + 256;
    float* sums2 = S + 512,  *aff2 = S + 768;
    float* sums3 = S + 1024, *aff3 = S + 1152;
    // aliases of Hbase (disjoint lifetimes, stream-ordered):
    float*  XA    = Hbase;                   // N*24 f32 (layer-1 pre-agg out)
    __half* Hh    = (__half*)Hbase;          // N*128 fp16 pre-scaled Ĥ (layers 2/3)
    float*  LG    = Hbase;                   // N*2 pre-scaled logits (layer 4)
    // alias of A (dead until gemm1 writes it):
    __half* xh    = (__half*)A;              // N*24 fp16 pre-scaled x̂

    hipMemsetAsync(S, 0, 1280 * sizeof(float), stream);

    const int TB = 256;
    const int nb1024 = (N + 1023) / 1024;

    // ---- CSR build + dinv ----
    k_zero_i<<<(N + TB - 1) / TB, TB, 0, stream>>>(cnt, N);
    k_count<<<(E + TB - 1) / TB, TB, 0, stream>>>(dstI, cnt, E);
    k_dinv<<<(N + TB - 1) / TB, TB, 0, stream>>>(cnt, dinv, N);
    k_scan1<<<nb1024, 1024, 0, stream>>>(cnt, rs, bsum, N);
    k_scan2<<<1, 1024, 0, stream>>>(bsum, nb1024);
    k_scan3<<<(N + TB - 1) / TB, TB, 0, stream>>>(rs, cur, bsum, N);
    k_fillx<<<256 * 8, TB, 0, stream>>>(srcI, dstI, cur, csrc, E, 256);
    // after k_fillx, cur[d] == row end

    // ----- layer 1: pre-scaled fp16 x̂, pre-aggregate (24-wide), GEMM + epilogue -----
    k_x2h<<<(N * 6 + TB - 1) / TB, TB, 0, stream>>>(x, dinv, xh, N);
    k_agg24h<<<2048, 256, 0, stream>>>(xh, rs, cur, csrc, dinv, XA, N);
    k_gemm2<24, 128, 4, false, true><<<1024, 256, 0, stream>>>(XA, W1, nullptr, A, b1, sums1, nullptr, N);
    k_bnprep<<<1, 128, 0, stream>>>(sums1, g1, be1, aff1, 128, 1.0f / (float)N);

    // ----- layer 2: GEMM 128->128 (fp16 Ĥ out), gather agg -----
    k_gemm2<128, 128, 4, true, false><<<1024, 256, 0, stream>>>(A, W2, aff1, Hh, nullptr, nullptr, dinv, N);
    k_aggh<128><<<2048, 256, 0, stream>>>((const __half2*)Hh, rs, cur, csrc, dinv, b2, A, sums2, N);
    k_bnprep<<<1, 128, 0, stream>>>(sums2, g2, be2, aff2, 128, 1.0f / (float)N);

    // ----- layer 3: GEMM 128->64 (fp16 Ĥ out), gather agg -----
    k_gemm2<128, 64, 2, true, false><<<1024, 256, 0, stream>>>(A, W3, aff2, Hh, nullptr, nullptr, dinv, N);
    k_aggh<64><<<2048, 256, 0, stream>>>((const __half2*)Hh, rs, cur, csrc, dinv, b3, A, sums3, N);
    k_bnprep<<<1, 64, 0, stream>>>(sums3, g3, be3, aff3, 64, 1.0f / (float)N);

    // ----- layer 4: 64 -> 2 (pre-scaled), log_softmax -----
    k_gemm4<<<(N + TB - 1) / TB, TB, 0, stream>>>(A, W4, aff3, dinv, LG, N);
    k_last<<<(N + TB - 1) / TB, TB, 0, stream>>>(LG, rs, cur, csrc, dinv, b4, out, N);
}